// Round 7
// baseline (878.925 us; speedup 1.0000x reference)
//
#include <hip/hip_runtime.h>
#include <hip/hip_bf16.h>
#include <math.h>

#define NEG_SLOPE 0.2f
#define CHUNK 6144         // edges staged per block in k_scatA

typedef short bf16x8 __attribute__((ext_vector_type(8)));
typedef float f32x4  __attribute__((ext_vector_type(4)));

__device__ __forceinline__ float leaky(float x){ return x > 0.f ? x : NEG_SLOPE*x; }
__device__ __forceinline__ float elu(float x){ return x > 0.f ? x : expm1f(x); }

__device__ __forceinline__ ushort f2bf(float f){
  uint u = __float_as_uint(f);
  u += 0x7fffu + ((u >> 16) & 1u);            // RNE
  return (ushort)(u >> 16);
}
__device__ __forceinline__ uint pk2(float lo, float hi){
  return (uint)f2bf(lo) | ((uint)f2bf(hi) << 16);
}
__device__ __forceinline__ float2 bfpair(uint v){   // uint = two packed bf16 (lo = even ch)
  return make_float2(__uint_as_float(v << 16), __uint_as_float(v & 0xffff0000u));
}

// ---------- W repack with ATTENTION AUGMENTATION ----------
// Emits NT+1 tiles of B-fragment-ordered bf16. Tiles 0..NT-1 = W columns.
// Tile NT col j: j<H -> sum_c W[k][j*32+c]*a_s[j][c]; H<=j<2H -> a_d; else 0.
template<int NT, int H>
__device__ __forceinline__ void wrep_dev(const float* __restrict__ W,
                    const float* __restrict__ a_s, const float* __restrict__ a_d,
                    ushort* __restrict__ Wf, int idx){
  constexpr int NTT = NT + 1;
  constexpr int M = NT*16;
  if (idx >= NTT*4*64) return;
  int lane = idx & 63;
  int c = (idx >> 6) & 3;
  int t = idx >> 8;
  int j = lane & 15;
  int k0 = c*32 + (lane >> 4)*8;
  float vals[8];
  if (t < NT){
    int col = t*16 + j;
    const float* p0 = W + (size_t)k0*M + col;
    #pragma unroll
    for (int r = 0; r < 8; r++) vals[r] = p0[(size_t)r*M];
  } else {
    #pragma unroll
    for (int r = 0; r < 8; r++) vals[r] = 0.f;
    if (j < 2*H){
      int h = (j < H) ? j : (j - H);
      const float* av = (j < H) ? (a_s + h*32) : (a_d + h*32);
      #pragma unroll
      for (int r = 0; r < 8; r++){
        const float* wr = W + (size_t)(k0 + r)*M + h*32;
        float s = 0.f;
        for (int cc = 0; cc < 32; cc++) s += wr[cc]*av[cc];
        vals[r] = s;
      }
    }
  }
  uint4 o;
  o.x = pk2(vals[0], vals[1]); o.y = pk2(vals[2], vals[3]);
  o.z = pk2(vals[4], vals[5]); o.w = pk2(vals[6], vals[7]);
  *(uint4*)(Wf + (size_t)idx*8) = o;
}

// ---------- PREP: wrep(all 3) + pool/done zero + graph bounds + dst histogram ----------
// All phases independent; routed by block range. One dispatch replaces 4.
__global__ __launch_bounds__(256) void k_prep(
    const float* __restrict__ W1, const float* __restrict__ as1, const float* __restrict__ ad1, ushort* __restrict__ Wf1,
    const float* __restrict__ W2, const float* __restrict__ as2, const float* __restrict__ ad2, ushort* __restrict__ Wf2,
    const float* __restrict__ W3, const float* __restrict__ as3, const float* __restrict__ ad3, ushort* __restrict__ Wf3,
    const int* __restrict__ ei, int E, int* __restrict__ bucketCount,
    const int* __restrict__ batch, int N, int G, int* __restrict__ gstart,
    float* __restrict__ pool, int* __restrict__ done, int NBb){
  __shared__ int hist[512];
  int b = blockIdx.x;
  int tid = threadIdx.x;
  if (b < 9){ wrep_dev<8,4>(W1, as1, ad1, Wf1, b*256 + tid); return; }
  if (b < 18){ wrep_dev<8,4>(W2, as2, ad2, Wf2, (b-9)*256 + tid); return; }
  if (b < 21){ wrep_dev<2,1>(W3, as3, ad3, Wf3, (b-18)*256 + tid); return; }
  if (b == 21){
    for (int i = tid; i < G*16; i += 256) pool[i] = 0.f;
    if (tid == 0) *done = 0;
    return;
  }
  b -= 22;
  if (b < NBb){
    int i = b*256 + tid;
    if (i >= N) return;
    int bb = batch[i];
    int bp = (i > 0) ? batch[i-1] : -1;
    for (int g = bp + 1; g <= bb; g++) gstart[g] = i;
    if (i == N-1){
      for (int g = bb + 1; g <= G; g++) gstart[g] = N;
    }
    return;
  }
  b -= NBb;
  // histogram phase (bucketCount zeroed by preceding memset)
  for (int k = tid; k < 512; k += 256) hist[k] = 0;
  __syncthreads();
  int base = b * 2048;
  int cnt = min(2048, E - base);
  for (int i = tid; i < cnt; i += 256)
    atomicAdd(&hist[ei[E + base + i] >> 8], 1);
  __syncthreads();
  for (int k = tid; k < 512; k += 256)
    if (hist[k]) atomicAdd(&bucketCount[k], hist[k]);
}

// ---------- scatter into dst-bucketed order (scan of bucketCount done locally) ----------
__global__ __launch_bounds__(256) void k_scatA(const int* __restrict__ ei, int E, int NB,
                         const int* __restrict__ bucketCount,
                         int* __restrict__ gcursor, uint* __restrict__ tmp){
  __shared__ uint stageS[CHUNK];
  __shared__ uint stageD[CHUNK];
  __shared__ int hist[512], pre[512], cur[512], gbase[512], bbase[512];
  __shared__ int scanArr[256];
  int tid = threadIdx.x;
  int base = blockIdx.x * CHUNK;
  int cnt = min(CHUNK, E - base);
  // global bucket-base scan (replaces the k_scanB dispatch)
  int c0 = (2*tid < NB) ? bucketCount[2*tid] : 0;
  int c1 = (2*tid+1 < NB) ? bucketCount[2*tid+1] : 0;
  scanArr[tid] = c0 + c1;
  __syncthreads();
  for (int st = 1; st < 256; st <<= 1){
    int v = (tid >= st) ? scanArr[tid - st] : 0;
    __syncthreads();
    scanArr[tid] += v;
    __syncthreads();
  }
  int gb = tid ? scanArr[tid-1] : 0;
  bbase[2*tid] = gb;
  bbase[2*tid+1] = gb + c0;
  // local chunk histogram
  hist[2*tid] = 0; hist[2*tid+1] = 0;
  __syncthreads();
  for (int i = tid; i < cnt; i += 256)
    atomicAdd(&hist[ei[E + base + i] >> 8], 1);
  __syncthreads();
  int a0 = hist[2*tid], a1 = hist[2*tid+1];
  scanArr[tid] = a0 + a1;
  __syncthreads();
  for (int st = 1; st < 256; st <<= 1){
    int v = (tid >= st) ? scanArr[tid - st] : 0;
    __syncthreads();
    scanArr[tid] += v;
    __syncthreads();
  }
  int eb = tid ? scanArr[tid-1] : 0;
  pre[2*tid] = eb;        cur[2*tid] = eb;
  pre[2*tid+1] = eb + a0; cur[2*tid+1] = eb + a0;
  if (2*tid < NB && a0 > 0)   gbase[2*tid]   = bbase[2*tid]   + atomicAdd(&gcursor[2*tid],   a0);
  if (2*tid+1 < NB && a1 > 0) gbase[2*tid+1] = bbase[2*tid+1] + atomicAdd(&gcursor[2*tid+1], a1);
  __syncthreads();
  for (int i = tid; i < cnt; i += 256){
    int s = ei[base + i];
    int d = ei[E + base + i];
    int lpos = atomicAdd(&cur[d >> 8], 1);
    stageS[lpos] = (uint)s; stageD[lpos] = (uint)d;
  }
  __syncthreads();
  for (int i = tid; i < cnt; i += 256){
    uint d = stageD[i];
    int b = d >> 8;
    tmp[gbase[b] + (i - pre[b])] = (stageS[i] << 8) | (d & 255u);
  }
}

__global__ __launch_bounds__(256) void k_csr(const uint* __restrict__ tmp,
                      const int* __restrict__ bucketCount,
                      int N, int NB, int* __restrict__ offsets, int* __restrict__ csr){
  int b = blockIdx.x;
  int nodeBase = b << 8;
  int nNodes = min(256, N - nodeBase);
  int tid = threadIdx.x;
  __shared__ int red[256];
  int partial = 0;
  for (int i = tid; i < b; i += 256) partial += bucketCount[i];
  red[tid] = partial;
  __syncthreads();
  for (int st = 128; st; st >>= 1){
    if (tid < st) red[tid] += red[tid + st];
    __syncthreads();
  }
  int eBeg = red[0];
  int eEnd = eBeg + bucketCount[b];
  __shared__ int deg[256], cur[256];
  deg[tid] = 0;
  __syncthreads();
  for (int e = eBeg + tid; e < eEnd; e += 256)
    atomicAdd(&deg[tmp[e] & 255u], 1);
  __syncthreads();
  cur[tid] = deg[tid];
  __syncthreads();
  for (int st = 1; st < 256; st <<= 1){
    int w = (tid >= st) ? cur[tid - st] : 0;
    __syncthreads();
    cur[tid] += w;
    __syncthreads();
  }
  int excl = tid ? cur[tid-1] : 0;
  __syncthreads();
  cur[tid] = excl;
  if (tid < nNodes) offsets[nodeBase + tid] = eBeg + excl;
  if (b == NB-1 && tid == 0) offsets[N] = eEnd;
  __syncthreads();
  for (int e = eBeg + tid; e < eEnd; e += 256){
    uint u = tmp[e];
    int lpos = atomicAdd(&cur[u & 255u], 1);
    csr[eBeg + lpos] = (int)(u >> 8);
  }
}

// ---------- MFMA GEMM: Y[n, NT*16](bf16) = X[n,128] @ W, plus fused asrc/adst ----------
template<int NT, bool A_F32, int H>
__global__ __launch_bounds__(256) void k_mgemm(const void* __restrict__ Xv,
                     const ushort* __restrict__ Wf, ushort* __restrict__ Y,
                     float* __restrict__ asrc, float* __restrict__ adst, int n){
  constexpr int NTT = NT + 1;
  constexpr int M = NT*16;
  int lane = threadIdx.x & 63;
  int l15 = lane & 15, q = lane >> 4;
  int wgid = blockIdx.x*4 + (threadIdx.x >> 6);
  int nchunks = (n + 15) >> 4;
  int stride = gridDim.x*4;

  bf16x8 bw[NTT][4];
  #pragma unroll
  for (int t = 0; t < NTT; t++)
    #pragma unroll
    for (int c = 0; c < 4; c++)
      bw[t][c] = *(const bf16x8*)(Wf + (size_t)(((t<<2)+c)*64 + lane)*8);

  int chunk = wgid;
  if (chunk >= nchunks) return;

  bf16x8 aCur[4], aNext[4];
  auto loadA = [&](int ck, bf16x8* a){
    int m = ck*16 + l15;
    if (m >= n) m = n - 1;
    if (A_F32){
      const float* X = (const float*)Xv + (size_t)m*128 + q*8;
      #pragma unroll
      for (int c = 0; c < 4; c++){
        float4 u0 = *(const float4*)(X + c*32);
        float4 u1 = *(const float4*)(X + c*32 + 4);
        uint4 pkd;
        pkd.x = pk2(u0.x, u0.y); pkd.y = pk2(u0.z, u0.w);
        pkd.z = pk2(u1.x, u1.y); pkd.w = pk2(u1.z, u1.w);
        union { uint4 u; bf16x8 v; } cv; cv.u = pkd;
        a[c] = cv.v;
      }
    } else {
      const ushort* X = (const ushort*)Xv + (size_t)m*128 + q*8;
      #pragma unroll
      for (int c = 0; c < 4; c++) a[c] = *(const bf16x8*)(X + c*32);
    }
  };

  loadA(chunk, aCur);
  while (true){
    int nx = chunk + stride;
    if (nx < nchunks) loadA(nx, aNext);
    f32x4 acc[NTT];
    #pragma unroll
    for (int t = 0; t < NTT; t++) acc[t] = (f32x4){0.f,0.f,0.f,0.f};
    #pragma unroll
    for (int c = 0; c < 4; c++)
      #pragma unroll
      for (int t = 0; t < NTT; t++)
        acc[t] = __builtin_amdgcn_mfma_f32_16x16x32_bf16(aCur[c], bw[t][c], acc[t], 0, 0, 0);
    int rowb = chunk*16 + q*4;
    #pragma unroll
    for (int t = 0; t < NT; t++)
      #pragma unroll
      for (int r = 0; r < 4; r++){
        int row = rowb + r;
        if (row < n) Y[(size_t)row*M + t*16 + l15] = f2bf(acc[t][r]);
      }
    // augmented tile -> asrc/adst
    #pragma unroll
    for (int r = 0; r < 4; r++){
      int row = rowb + r;
      if (row < n){
        float v = acc[NT][r];
        if (l15 < H)           asrc[(size_t)row*H + l15]       = v;
        else if (l15 < 2*H)    adst[(size_t)row*H + (l15 - H)] = v;
      }
    }
    if (nx >= nchunks) break;
    chunk = nx;
    #pragma unroll
    for (int c = 0; c < 4; c++) aCur[c] = aNext[c];
  }
}

// ---------- FUSED per-dst aggregation for HC=128 (H=4) ----------
// One node per wave (proven shape: VGPR 32, occ ~78%). Edge indices in a
// register; readlane -> SGPR row base + shared lane voffset. Weights staged
// via LDS. Ping-pong 8-edge groups: 16 row loads in flight. No barriers.
template<bool OUT_BF16>
__global__ __launch_bounds__(256) void k_agg128f(const ushort* __restrict__ Hb,
                    const float* __restrict__ asrc, const float* __restrict__ adst,
                    const int* __restrict__ offsets, const int* __restrict__ csr_src,
                    const float* __restrict__ bias, void* __restrict__ Out, int n){
  __shared__ float lwAll[4][256];     // 64 edges x 4 heads per wave
  int wv = threadIdx.x >> 6;
  int lane = threadIdx.x & 63;
  float* lw = lwAll[wv];
  int node = blockIdx.x*4 + wv;
  if (node >= n) return;
  const int up = lane, ch = up*2, h0 = up >> 4;
  const uint* rows = (const uint*)Hb;
  int j0 = offsets[node], end = offsets[node+1];   // issue early
  float4 adv = *(const float4*)(adst + (size_t)node*4);
  float adh = (h0==0)?adv.x:(h0==1)?adv.y:(h0==2)?adv.z:adv.w;
  float acc0 = 0.f, acc1 = 0.f, den = 0.f;
  // self loop
  {
    float w = __expf(leaky(asrc[(size_t)node*4 + h0] + adh));
    float2 f = bfpair(rows[(size_t)node*64 + up]);
    den += w; acc0 += w*f.x; acc1 += w*f.y;
  }
  for (int base = j0; base < end; base += 64){
    int m = min(64, end - base);
    int mR = (m + 7) & ~7;              // pad to full groups of 8 (w=0, s=node)
    int sreg = node;
    if (lane < m){
      sreg = csr_src[base + lane];
      float4 a = *(const float4*)(asrc + (size_t)sreg*4);
      float4 w4;
      w4.x = __expf(leaky(a.x + adv.x));
      w4.y = __expf(leaky(a.y + adv.y));
      w4.z = __expf(leaky(a.z + adv.z));
      w4.w = __expf(leaky(a.w + adv.w));
      *(float4*)(lw + lane*4) = w4;
    } else if (lane < mR){
      *(float4*)(lw + lane*4) = make_float4(0.f, 0.f, 0.f, 0.f);
    }
    uint rA[8]; float wA[8];
    uint rB[8]; float wB[8];
    auto loadGroup = [&](int e, uint* r, float* w){
      #pragma unroll
      for (int k = 0; k < 8; k++){
        int s = __builtin_amdgcn_readlane(sreg, e + k);   // SGPR index
        r[k] = rows[(size_t)(uint)s*64 + up];             // scalar base + lane voffset
      }
      #pragma unroll
      for (int k = 0; k < 8; k++) w[k] = lw[(e + k)*4 + h0];
    };
    auto consume = [&](const uint* r, const float* w){
      #pragma unroll
      for (int k = 0; k < 8; k++){
        float2 f = bfpair(r[k]);
        den += w[k]; acc0 += w[k]*f.x; acc1 += w[k]*f.y;
      }
    };
    loadGroup(0, rA, wA);
    int e = 8;
    for (; e + 16 <= mR; e += 16){
      loadGroup(e, rB, wB);
      consume(rA, wA);
      loadGroup(e + 8, rA, wA);
      consume(rB, wB);
    }
    if (e < mR){
      loadGroup(e, rB, wB);
      consume(rA, wA);
      consume(rB, wB);
    } else {
      consume(rA, wA);
    }
  }
  float inv = 1.f/(den + 1e-16f);
  float ox = elu(acc0*inv + bias[ch]);
  float oy = elu(acc1*inv + bias[ch+1]);
  if (OUT_BF16){
    ((uint*)Out)[(size_t)node*64 + up] = pk2(ox, oy);
  } else {
    *(float2*)((float*)Out + (size_t)node*128 + ch) = make_float2(ox, oy);
  }
}

// ---------- layer-3 aggregation (HC=32, H=1) + readout dot + pool + FINISH ----------
// 4 nodes per wave. After elu, dot with fc_w, atomicAdd into spread pool slots.
// Completion counter: last block to finish computes the per-graph means and
// writes the final output (replaces the k_poolfin dispatch). Pool reads in the
// finisher use atomicAdd(p, 0.f) for cross-XCD coherence.
__global__ __launch_bounds__(256) void k_agg32pool(const ushort* __restrict__ Hb,
                    const float* __restrict__ asrc, const float* __restrict__ adst,
                    const int* __restrict__ offsets, const int* __restrict__ csr_src,
                    const float* __restrict__ bias, const float* __restrict__ fcw,
                    const int* __restrict__ batch, float* __restrict__ pool, int n,
                    const int* __restrict__ gstart, const float* __restrict__ fcb,
                    float* __restrict__ out, int* __restrict__ done, int G){
  __shared__ int   lsAll[4][4][16];
  __shared__ float lwAll[4][4][16];
  __shared__ int lastFlag;
  int wv = threadIdx.x >> 6;
  int lane = threadIdx.x & 63;
  int g = lane >> 4, i = lane & 15;
  int node = (blockIdx.x*4 + wv)*4 + g;
  if (node < n){
    int* ls = lsAll[wv][g];
    float* lw = lwAll[wv][g];
    const uint* rows = (const uint*)Hb;
    float adn = adst[node];
    float acc0 = 0.f, acc1 = 0.f, den = 0.f;
    // self loop
    {
      float w = __expf(leaky(asrc[node] + adn));
      float2 f = bfpair(rows[(size_t)node*16 + i]);
      den += w; acc0 += w*f.x; acc1 += w*f.y;
    }
    int j0 = offsets[node], end = offsets[node+1];
    for (int base = j0; base < end; base += 16){
      int m = min(16, end - base);
      {
        int idx = base + i;
        bool v = idx < end;
        int s = v ? csr_src[idx] : node;
        ls[i] = s;
        lw[i] = v ? __expf(leaky(asrc[s] + adn)) : 0.f;
      }
      int mR = (m + 3) & ~3;
      for (int e = 0; e < mR; e += 4){
        int s0 = ls[e], s1 = ls[e+1], s2 = ls[e+2], s3 = ls[e+3];
        float w0 = lw[e], w1 = lw[e+1], w2 = lw[e+2], w3 = lw[e+3];
        uint r0 = rows[(size_t)s0*16 + i];
        uint r1 = rows[(size_t)s1*16 + i];
        uint r2 = rows[(size_t)s2*16 + i];
        uint r3 = rows[(size_t)s3*16 + i];
        float2 f0 = bfpair(r0), f1 = bfpair(r1), f2 = bfpair(r2), f3 = bfpair(r3);
        den  += (w0 + w1) + (w2 + w3);
        acc0 += w0*f0.x + w1*f1.x + w2*f2.x + w3*f3.x;
        acc1 += w0*f0.y + w1*f1.y + w2*f2.y + w3*f3.y;
      }
    }
    float inv = 1.f/(den + 1e-16f);
    int ch = i*2;
    float2 fw = *(const float2*)(fcw + ch);
    float t = elu(acc0*inv + bias[ch])*fw.x + elu(acc1*inv + bias[ch+1])*fw.y;
    #pragma unroll
    for (int off = 1; off < 16; off <<= 1) t += __shfl_xor(t, off, 16);
    if (i == 0){
      atomicAdd(&pool[(size_t)batch[node]*16 + (node & 15)], t);
      __threadfence();          // make this block's pool atomics device-visible
    }
  }
  __syncthreads();
  if (threadIdx.x == 0){
    int old = atomicAdd(done, 1);
    lastFlag = (old == (int)gridDim.x - 1) ? 1 : 0;
  }
  __syncthreads();
  if (lastFlag){
    for (int gg = threadIdx.x; gg < G; gg += 256){
      float s = 0.f;
      #pragma unroll
      for (int k = 0; k < 16; k++)
        s += atomicAdd(&pool[(size_t)gg*16 + k], 0.f);   // coherent read
      float cnt = (float)(gstart[gg+1] - gstart[gg]);
      if (cnt < 1.f) cnt = 1.f;
      out[gg] = s/cnt + fcb[0];
    }
  }
}

extern "C" void kernel_launch(void* const* d_in, const int* in_sizes, int n_in,
                              void* d_out, int out_size, void* d_ws, size_t ws_size,
                              hipStream_t stream){
  const float* x    = (const float*)d_in[0];
  const int*   ei   = (const int*)d_in[1];
  const int*   batch= (const int*)d_in[2];
  const float* W1   = (const float*)d_in[3];
  const float* as1  = (const float*)d_in[4];
  const float* ad1  = (const float*)d_in[5];
  const float* b1   = (const float*)d_in[6];
  const float* W2   = (const float*)d_in[7];
  const float* as2  = (const float*)d_in[8];
  const float* ad2  = (const float*)d_in[9];
  const float* b2   = (const float*)d_in[10];
  const float* W3   = (const float*)d_in[11];
  const float* as3  = (const float*)d_in[12];
  const float* ad3  = (const float*)d_in[13];
  const float* b3   = (const float*)d_in[14];
  const float* fcw  = (const float*)d_in[15];
  const float* fcb  = (const float*)d_in[16];
  float* out = (float*)d_out;

  const int N = in_sizes[0] / 128;
  const int E = in_sizes[1] / 2;
  const int G = out_size;
  const int NB = (N + 255) >> 8;

  char* p = (char*)d_ws;
  auto alloc = [&](size_t bytes) -> void* {
    void* r = (void*)p;
    p += (bytes + 255) & ~(size_t)255;
    return r;
  };
  ushort* bufH   = (ushort*)alloc((size_t)N*128*sizeof(ushort));  // GEMM out (bf16)
  ushort* aggB   = (ushort*)alloc((size_t)N*128*sizeof(ushort));  // agg out L1/L2 (bf16)
  ushort* bufH3  = (ushort*)alloc((size_t)N*32*sizeof(ushort));   // GEMM3 out (bf16)
  float*  asrcA  = (float*)alloc((size_t)N*4*sizeof(float));
  float*  adstA  = (float*)alloc((size_t)N*4*sizeof(float));
  float*  asrcB  = (float*)alloc((size_t)N*4*sizeof(float));
  float*  adstB  = (float*)alloc((size_t)N*4*sizeof(float));
  int*    offsets= (int*)alloc((size_t)(N+1)*sizeof(int));
  int*    csr    = (int*)alloc((size_t)E*sizeof(int));
  uint*   tmp    = (uint*)alloc((size_t)E*sizeof(uint));
  int*    zeroR  = (int*)alloc(1024*sizeof(int));   // bCount[512] + gcursor[512]
  int*    bCount = zeroR;
  int*    gcursor= zeroR + 512;
  int*    gstart = (int*)alloc((size_t)(G+1)*sizeof(int));
  float*  pool   = (float*)alloc((size_t)G*16*sizeof(float));
  int*    done   = (int*)alloc(256);
  ushort* Wf1    = (ushort*)alloc(9*4*64*8*sizeof(ushort));
  ushort* Wf2    = (ushort*)alloc(9*4*64*8*sizeof(ushort));
  ushort* Wf3    = (ushort*)alloc(3*4*64*8*sizeof(ushort));

  hipMemsetAsync(zeroR, 0, 1024*sizeof(int), stream);

  const int NBb = (N + 255)/256;
  const int NH  = (E + 2047)/2048;
  // prep: wrep(21) + zero(1) + bounds(NBb) + hist(NH) in one dispatch
  k_prep<<<22 + NBb + NH, 256, 0, stream>>>(W1, as1, ad1, Wf1, W2, as2, ad2, Wf2,
                                            W3, as3, ad3, Wf3, ei, E, bCount,
                                            batch, N, G, gstart, pool, done, NBb);
  k_scatA<<<(E+CHUNK-1)/CHUNK, 256, 0, stream>>>(ei, E, NB, bCount, gcursor, tmp);
  k_csr<<<NB, 256, 0, stream>>>(tmp, bCount, N, NB, offsets, csr);

  const int GB = (((N + 15)/16) + 3)/4;   // one 16-row chunk per wave
  const int NWB = (N + 3)/4;      // agg128: 4 nodes/block (1 per wave)
  const int NWB32 = (N + 15)/16;  // agg32pool: 16 nodes/block (4 per wave)
  // layer 1
  k_mgemm<8, true , 4><<<GB, 256, 0, stream>>>(x, Wf1, bufH, asrcA, adstA, N);
  k_agg128f<true><<<NWB, 256, 0, stream>>>(bufH, asrcA, adstA, offsets, csr, b1, aggB, N);
  // layer 2
  k_mgemm<8, false, 4><<<GB, 256, 0, stream>>>(aggB, Wf2, bufH, asrcB, adstB, N);
  k_agg128f<true><<<NWB, 256, 0, stream>>>(bufH, asrcB, adstB, offsets, csr, b2, aggB, N);
  // layer 3
  k_mgemm<2, false, 1><<<GB, 256, 0, stream>>>(aggB, Wf3, bufH3, asrcA, adstA, N);
  // layer-3 agg + readout dot + pool + finish (completion counter)
  k_agg32pool<<<NWB32, 256, 0, stream>>>(bufH3, asrcA, adstA, offsets, csr,
                                         b3, fcw, batch, pool, N,
                                         gstart, fcb, out, done, G);
}

// Round 8
// 416.204 us; speedup vs baseline: 2.1118x; 2.1118x over previous
//
#include <hip/hip_runtime.h>
#include <hip/hip_bf16.h>
#include <math.h>

#define NEG_SLOPE 0.2f
#define CHUNK 6144         // edges staged per block in k_scatA

typedef short bf16x8 __attribute__((ext_vector_type(8)));
typedef float f32x4  __attribute__((ext_vector_type(4)));

__device__ __forceinline__ float leaky(float x){ return x > 0.f ? x : NEG_SLOPE*x; }
__device__ __forceinline__ float elu(float x){ return x > 0.f ? x : expm1f(x); }

__device__ __forceinline__ ushort f2bf(float f){
  uint u = __float_as_uint(f);
  u += 0x7fffu + ((u >> 16) & 1u);            // RNE
  return (ushort)(u >> 16);
}
__device__ __forceinline__ uint pk2(float lo, float hi){
  return (uint)f2bf(lo) | ((uint)f2bf(hi) << 16);
}
__device__ __forceinline__ float2 bfpair(uint v){   // uint = two packed bf16 (lo = even ch)
  return make_float2(__uint_as_float(v << 16), __uint_as_float(v & 0xffff0000u));
}

// ---------- W repack with ATTENTION AUGMENTATION ----------
// Emits NT+1 tiles of B-fragment-ordered bf16. Tiles 0..NT-1 = W columns.
// Tile NT col j: j<H -> sum_c W[k][j*32+c]*a_s[j][c]; H<=j<2H -> a_d; else 0.
template<int NT, int H>
__device__ __forceinline__ void wrep_dev(const float* __restrict__ W,
                    const float* __restrict__ a_s, const float* __restrict__ a_d,
                    ushort* __restrict__ Wf, int idx){
  constexpr int NTT = NT + 1;
  constexpr int M = NT*16;
  if (idx >= NTT*4*64) return;
  int lane = idx & 63;
  int c = (idx >> 6) & 3;
  int t = idx >> 8;
  int j = lane & 15;
  int k0 = c*32 + (lane >> 4)*8;
  float vals[8];
  if (t < NT){
    int col = t*16 + j;
    const float* p0 = W + (size_t)k0*M + col;
    #pragma unroll
    for (int r = 0; r < 8; r++) vals[r] = p0[(size_t)r*M];
  } else {
    #pragma unroll
    for (int r = 0; r < 8; r++) vals[r] = 0.f;
    if (j < 2*H){
      int h = (j < H) ? j : (j - H);
      const float* av = (j < H) ? (a_s + h*32) : (a_d + h*32);
      #pragma unroll
      for (int r = 0; r < 8; r++){
        const float* wr = W + (size_t)(k0 + r)*M + h*32;
        float s = 0.f;
        for (int cc = 0; cc < 32; cc++) s += wr[cc]*av[cc];
        vals[r] = s;
      }
    }
  }
  uint4 o;
  o.x = pk2(vals[0], vals[1]); o.y = pk2(vals[2], vals[3]);
  o.z = pk2(vals[4], vals[5]); o.w = pk2(vals[6], vals[7]);
  *(uint4*)(Wf + (size_t)idx*8) = o;
}

// ---------- PREP: wrep(all 3) + pool zero + graph bounds + dst histogram ----------
// All phases independent; routed by block range. One dispatch replaces 4.
__global__ __launch_bounds__(256) void k_prep(
    const float* __restrict__ W1, const float* __restrict__ as1, const float* __restrict__ ad1, ushort* __restrict__ Wf1,
    const float* __restrict__ W2, const float* __restrict__ as2, const float* __restrict__ ad2, ushort* __restrict__ Wf2,
    const float* __restrict__ W3, const float* __restrict__ as3, const float* __restrict__ ad3, ushort* __restrict__ Wf3,
    const int* __restrict__ ei, int E, int* __restrict__ bucketCount,
    const int* __restrict__ batch, int N, int G, int* __restrict__ gstart,
    float* __restrict__ pool, int NBb){
  __shared__ int hist[512];
  int b = blockIdx.x;
  int tid = threadIdx.x;
  if (b < 9){ wrep_dev<8,4>(W1, as1, ad1, Wf1, b*256 + tid); return; }
  if (b < 18){ wrep_dev<8,4>(W2, as2, ad2, Wf2, (b-9)*256 + tid); return; }
  if (b < 21){ wrep_dev<2,1>(W3, as3, ad3, Wf3, (b-18)*256 + tid); return; }
  if (b == 21){
    for (int i = tid; i < G*16; i += 256) pool[i] = 0.f;
    return;
  }
  b -= 22;
  if (b < NBb){
    int i = b*256 + tid;
    if (i >= N) return;
    int bb = batch[i];
    int bp = (i > 0) ? batch[i-1] : -1;
    for (int g = bp + 1; g <= bb; g++) gstart[g] = i;
    if (i == N-1){
      for (int g = bb + 1; g <= G; g++) gstart[g] = N;
    }
    return;
  }
  b -= NBb;
  // histogram phase (bucketCount zeroed by preceding memset)
  for (int k = tid; k < 512; k += 256) hist[k] = 0;
  __syncthreads();
  int base = b * 2048;
  int cnt = min(2048, E - base);
  for (int i = tid; i < cnt; i += 256)
    atomicAdd(&hist[ei[E + base + i] >> 8], 1);
  __syncthreads();
  for (int k = tid; k < 512; k += 256)
    if (hist[k]) atomicAdd(&bucketCount[k], hist[k]);
}

// ---------- scatter into dst-bucketed order (scan of bucketCount done locally) ----------
__global__ __launch_bounds__(256) void k_scatA(const int* __restrict__ ei, int E, int NB,
                         const int* __restrict__ bucketCount,
                         int* __restrict__ gcursor, uint* __restrict__ tmp){
  __shared__ uint stageS[CHUNK];
  __shared__ uint stageD[CHUNK];
  __shared__ int hist[512], pre[512], cur[512], gbase[512], bbase[512];
  __shared__ int scanArr[256];
  int tid = threadIdx.x;
  int base = blockIdx.x * CHUNK;
  int cnt = min(CHUNK, E - base);
  // global bucket-base scan (replaces the k_scanB dispatch)
  int c0 = (2*tid < NB) ? bucketCount[2*tid] : 0;
  int c1 = (2*tid+1 < NB) ? bucketCount[2*tid+1] : 0;
  scanArr[tid] = c0 + c1;
  __syncthreads();
  for (int st = 1; st < 256; st <<= 1){
    int v = (tid >= st) ? scanArr[tid - st] : 0;
    __syncthreads();
    scanArr[tid] += v;
    __syncthreads();
  }
  int gb = tid ? scanArr[tid-1] : 0;
  bbase[2*tid] = gb;
  bbase[2*tid+1] = gb + c0;
  // local chunk histogram
  hist[2*tid] = 0; hist[2*tid+1] = 0;
  __syncthreads();
  for (int i = tid; i < cnt; i += 256)
    atomicAdd(&hist[ei[E + base + i] >> 8], 1);
  __syncthreads();
  int a0 = hist[2*tid], a1 = hist[2*tid+1];
  scanArr[tid] = a0 + a1;
  __syncthreads();
  for (int st = 1; st < 256; st <<= 1){
    int v = (tid >= st) ? scanArr[tid - st] : 0;
    __syncthreads();
    scanArr[tid] += v;
    __syncthreads();
  }
  int eb = tid ? scanArr[tid-1] : 0;
  pre[2*tid] = eb;        cur[2*tid] = eb;
  pre[2*tid+1] = eb + a0; cur[2*tid+1] = eb + a0;
  if (2*tid < NB && a0 > 0)   gbase[2*tid]   = bbase[2*tid]   + atomicAdd(&gcursor[2*tid],   a0);
  if (2*tid+1 < NB && a1 > 0) gbase[2*tid+1] = bbase[2*tid+1] + atomicAdd(&gcursor[2*tid+1], a1);
  __syncthreads();
  for (int i = tid; i < cnt; i += 256){
    int s = ei[base + i];
    int d = ei[E + base + i];
    int lpos = atomicAdd(&cur[d >> 8], 1);
    stageS[lpos] = (uint)s; stageD[lpos] = (uint)d;
  }
  __syncthreads();
  for (int i = tid; i < cnt; i += 256){
    uint d = stageD[i];
    int b = d >> 8;
    tmp[gbase[b] + (i - pre[b])] = (stageS[i] << 8) | (d & 255u);
  }
}

__global__ __launch_bounds__(256) void k_csr(const uint* __restrict__ tmp,
                      const int* __restrict__ bucketCount,
                      int N, int NB, int* __restrict__ offsets, int* __restrict__ csr){
  int b = blockIdx.x;
  int nodeBase = b << 8;
  int nNodes = min(256, N - nodeBase);
  int tid = threadIdx.x;
  __shared__ int red[256];
  int partial = 0;
  for (int i = tid; i < b; i += 256) partial += bucketCount[i];
  red[tid] = partial;
  __syncthreads();
  for (int st = 128; st; st >>= 1){
    if (tid < st) red[tid] += red[tid + st];
    __syncthreads();
  }
  int eBeg = red[0];
  int eEnd = eBeg + bucketCount[b];
  __shared__ int deg[256], cur[256];
  deg[tid] = 0;
  __syncthreads();
  for (int e = eBeg + tid; e < eEnd; e += 256)
    atomicAdd(&deg[tmp[e] & 255u], 1);
  __syncthreads();
  cur[tid] = deg[tid];
  __syncthreads();
  for (int st = 1; st < 256; st <<= 1){
    int w = (tid >= st) ? cur[tid - st] : 0;
    __syncthreads();
    cur[tid] += w;
    __syncthreads();
  }
  int excl = tid ? cur[tid-1] : 0;
  __syncthreads();
  cur[tid] = excl;
  if (tid < nNodes) offsets[nodeBase + tid] = eBeg + excl;
  if (b == NB-1 && tid == 0) offsets[N] = eEnd;
  __syncthreads();
  for (int e = eBeg + tid; e < eEnd; e += 256){
    uint u = tmp[e];
    int lpos = atomicAdd(&cur[u & 255u], 1);
    csr[eBeg + lpos] = (int)(u >> 8);
  }
}

// ---------- MFMA GEMM: Y[n, NT*16](bf16) = X[n,128] @ W, plus fused asrc/adst ----------
template<int NT, bool A_F32, int H>
__global__ __launch_bounds__(256) void k_mgemm(const void* __restrict__ Xv,
                     const ushort* __restrict__ Wf, ushort* __restrict__ Y,
                     float* __restrict__ asrc, float* __restrict__ adst, int n){
  constexpr int NTT = NT + 1;
  constexpr int M = NT*16;
  int lane = threadIdx.x & 63;
  int l15 = lane & 15, q = lane >> 4;
  int wgid = blockIdx.x*4 + (threadIdx.x >> 6);
  int nchunks = (n + 15) >> 4;
  int stride = gridDim.x*4;

  bf16x8 bw[NTT][4];
  #pragma unroll
  for (int t = 0; t < NTT; t++)
    #pragma unroll
    for (int c = 0; c < 4; c++)
      bw[t][c] = *(const bf16x8*)(Wf + (size_t)(((t<<2)+c)*64 + lane)*8);

  int chunk = wgid;
  if (chunk >= nchunks) return;

  bf16x8 aCur[4], aNext[4];
  auto loadA = [&](int ck, bf16x8* a){
    int m = ck*16 + l15;
    if (m >= n) m = n - 1;
    if (A_F32){
      const float* X = (const float*)Xv + (size_t)m*128 + q*8;
      #pragma unroll
      for (int c = 0; c < 4; c++){
        float4 u0 = *(const float4*)(X + c*32);
        float4 u1 = *(const float4*)(X + c*32 + 4);
        uint4 pkd;
        pkd.x = pk2(u0.x, u0.y); pkd.y = pk2(u0.z, u0.w);
        pkd.z = pk2(u1.x, u1.y); pkd.w = pk2(u1.z, u1.w);
        union { uint4 u; bf16x8 v; } cv; cv.u = pkd;
        a[c] = cv.v;
      }
    } else {
      const ushort* X = (const ushort*)Xv + (size_t)m*128 + q*8;
      #pragma unroll
      for (int c = 0; c < 4; c++) a[c] = *(const bf16x8*)(X + c*32);
    }
  };

  loadA(chunk, aCur);
  while (true){
    int nx = chunk + stride;
    if (nx < nchunks) loadA(nx, aNext);
    f32x4 acc[NTT];
    #pragma unroll
    for (int t = 0; t < NTT; t++) acc[t] = (f32x4){0.f,0.f,0.f,0.f};
    #pragma unroll
    for (int c = 0; c < 4; c++)
      #pragma unroll
      for (int t = 0; t < NTT; t++)
        acc[t] = __builtin_amdgcn_mfma_f32_16x16x32_bf16(aCur[c], bw[t][c], acc[t], 0, 0, 0);
    int rowb = chunk*16 + q*4;
    #pragma unroll
    for (int t = 0; t < NT; t++)
      #pragma unroll
      for (int r = 0; r < 4; r++){
        int row = rowb + r;
        if (row < n) Y[(size_t)row*M + t*16 + l15] = f2bf(acc[t][r]);
      }
    // augmented tile -> asrc/adst
    #pragma unroll
    for (int r = 0; r < 4; r++){
      int row = rowb + r;
      if (row < n){
        float v = acc[NT][r];
        if (l15 < H)           asrc[(size_t)row*H + l15]       = v;
        else if (l15 < 2*H)    adst[(size_t)row*H + (l15 - H)] = v;
      }
    }
    if (nx >= nchunks) break;
    chunk = nx;
    #pragma unroll
    for (int c = 0; c < 4; c++) aCur[c] = aNext[c];
  }
}

// ---------- FUSED per-dst aggregation for HC=128 (H=4) ----------
// One node per wave (proven shape: VGPR 32, occ ~78%). Edge indices in a
// register; readlane -> SGPR row base + shared lane voffset. Weights staged
// via LDS. Ping-pong 8-edge groups: 16 row loads in flight. No barriers.
template<bool OUT_BF16>
__global__ __launch_bounds__(256) void k_agg128f(const ushort* __restrict__ Hb,
                    const float* __restrict__ asrc, const float* __restrict__ adst,
                    const int* __restrict__ offsets, const int* __restrict__ csr_src,
                    const float* __restrict__ bias, void* __restrict__ Out, int n){
  __shared__ float lwAll[4][256];     // 64 edges x 4 heads per wave
  int wv = threadIdx.x >> 6;
  int lane = threadIdx.x & 63;
  float* lw = lwAll[wv];
  int node = blockIdx.x*4 + wv;
  if (node >= n) return;
  const int up = lane, ch = up*2, h0 = up >> 4;
  const uint* rows = (const uint*)Hb;
  int j0 = offsets[node], end = offsets[node+1];   // issue early
  float4 adv = *(const float4*)(adst + (size_t)node*4);
  float adh = (h0==0)?adv.x:(h0==1)?adv.y:(h0==2)?adv.z:adv.w;
  float acc0 = 0.f, acc1 = 0.f, den = 0.f;
  // self loop
  {
    float w = __expf(leaky(asrc[(size_t)node*4 + h0] + adh));
    float2 f = bfpair(rows[(size_t)node*64 + up]);
    den += w; acc0 += w*f.x; acc1 += w*f.y;
  }
  for (int base = j0; base < end; base += 64){
    int m = min(64, end - base);
    int mR = (m + 7) & ~7;              // pad to full groups of 8 (w=0, s=node)
    int sreg = node;
    if (lane < m){
      sreg = csr_src[base + lane];
      float4 a = *(const float4*)(asrc + (size_t)sreg*4);
      float4 w4;
      w4.x = __expf(leaky(a.x + adv.x));
      w4.y = __expf(leaky(a.y + adv.y));
      w4.z = __expf(leaky(a.z + adv.z));
      w4.w = __expf(leaky(a.w + adv.w));
      *(float4*)(lw + lane*4) = w4;
    } else if (lane < mR){
      *(float4*)(lw + lane*4) = make_float4(0.f, 0.f, 0.f, 0.f);
    }
    uint rA[8]; float wA[8];
    uint rB[8]; float wB[8];
    auto loadGroup = [&](int e, uint* r, float* w){
      #pragma unroll
      for (int k = 0; k < 8; k++){
        int s = __builtin_amdgcn_readlane(sreg, e + k);   // SGPR index
        r[k] = rows[(size_t)(uint)s*64 + up];             // scalar base + lane voffset
      }
      #pragma unroll
      for (int k = 0; k < 8; k++) w[k] = lw[(e + k)*4 + h0];
    };
    auto consume = [&](const uint* r, const float* w){
      #pragma unroll
      for (int k = 0; k < 8; k++){
        float2 f = bfpair(r[k]);
        den += w[k]; acc0 += w[k]*f.x; acc1 += w[k]*f.y;
      }
    };
    loadGroup(0, rA, wA);
    int e = 8;
    for (; e + 16 <= mR; e += 16){
      loadGroup(e, rB, wB);
      consume(rA, wA);
      loadGroup(e + 8, rA, wA);
      consume(rB, wB);
    }
    if (e < mR){
      loadGroup(e, rB, wB);
      consume(rA, wA);
      consume(rB, wB);
    } else {
      consume(rA, wA);
    }
  }
  float inv = 1.f/(den + 1e-16f);
  float ox = elu(acc0*inv + bias[ch]);
  float oy = elu(acc1*inv + bias[ch+1]);
  if (OUT_BF16){
    ((uint*)Out)[(size_t)node*64 + up] = pk2(ox, oy);
  } else {
    *(float2*)((float*)Out + (size_t)node*128 + ch) = make_float2(ox, oy);
  }
}

// ---------- layer-3 aggregation (HC=32, H=1) fused with readout dot+pool ----------
// 4 nodes per wave (g = lane>>4, i = lane&15). After elu, dot with fc_w and
// atomically accumulate per node into its graph's pool, spread over 16 sub-slots
// (pool[g*16 + node&15]). NO fences — finisher is a separate dispatch (r7's
// in-kernel finisher with per-node __threadfence cost 507us; measured).
__global__ __launch_bounds__(256) void k_agg32pool(const ushort* __restrict__ Hb,
                    const float* __restrict__ asrc, const float* __restrict__ adst,
                    const int* __restrict__ offsets, const int* __restrict__ csr_src,
                    const float* __restrict__ bias, const float* __restrict__ fcw,
                    const int* __restrict__ batch, float* __restrict__ pool, int n){
  __shared__ int   lsAll[4][4][16];
  __shared__ float lwAll[4][4][16];
  int wv = threadIdx.x >> 6;
  int lane = threadIdx.x & 63;
  int g = lane >> 4, i = lane & 15;
  int node = (blockIdx.x*4 + wv)*4 + g;
  if (node >= n) return;
  int* ls = lsAll[wv][g];
  float* lw = lwAll[wv][g];
  const uint* rows = (const uint*)Hb;
  float adn = adst[node];
  float acc0 = 0.f, acc1 = 0.f, den = 0.f;
  // self loop
  {
    float w = __expf(leaky(asrc[node] + adn));
    float2 f = bfpair(rows[(size_t)node*16 + i]);
    den += w; acc0 += w*f.x; acc1 += w*f.y;
  }
  int j0 = offsets[node], end = offsets[node+1];
  for (int base = j0; base < end; base += 16){
    int m = min(16, end - base);
    {
      int idx = base + i;
      bool v = idx < end;
      int s = v ? csr_src[idx] : node;
      ls[i] = s;
      lw[i] = v ? __expf(leaky(asrc[s] + adn)) : 0.f;
    }
    int mR = (m + 3) & ~3;
    for (int e = 0; e < mR; e += 4){
      int s0 = ls[e], s1 = ls[e+1], s2 = ls[e+2], s3 = ls[e+3];
      float w0 = lw[e], w1 = lw[e+1], w2 = lw[e+2], w3 = lw[e+3];
      uint r0 = rows[(size_t)s0*16 + i];
      uint r1 = rows[(size_t)s1*16 + i];
      uint r2 = rows[(size_t)s2*16 + i];
      uint r3 = rows[(size_t)s3*16 + i];
      float2 f0 = bfpair(r0), f1 = bfpair(r1), f2 = bfpair(r2), f3 = bfpair(r3);
      den  += (w0 + w1) + (w2 + w3);
      acc0 += w0*f0.x + w1*f1.x + w2*f2.x + w3*f3.x;
      acc1 += w0*f0.y + w1*f1.y + w2*f2.y + w3*f3.y;
    }
  }
  float inv = 1.f/(den + 1e-16f);
  int ch = i*2;
  float2 fw = *(const float2*)(fcw + ch);
  float t = elu(acc0*inv + bias[ch])*fw.x + elu(acc1*inv + bias[ch+1])*fw.y;
  #pragma unroll
  for (int off = 1; off < 16; off <<= 1) t += __shfl_xor(t, off, 16);
  if (i == 0) atomicAdd(&pool[(size_t)batch[node]*16 + (node & 15)], t);
}

__global__ __launch_bounds__(256) void k_poolfin(const float* __restrict__ pool,
                    const int* __restrict__ gstart, const float* __restrict__ fcb,
                    float* __restrict__ out, int G){
  int g = blockIdx.x*256 + threadIdx.x;
  if (g >= G) return;
  float s = 0.f;
  #pragma unroll
  for (int k = 0; k < 16; k++) s += pool[(size_t)g*16 + k];
  float cnt = (float)(gstart[g+1] - gstart[g]);
  if (cnt < 1.f) cnt = 1.f;
  out[g] = s/cnt + fcb[0];
}

extern "C" void kernel_launch(void* const* d_in, const int* in_sizes, int n_in,
                              void* d_out, int out_size, void* d_ws, size_t ws_size,
                              hipStream_t stream){
  const float* x    = (const float*)d_in[0];
  const int*   ei   = (const int*)d_in[1];
  const int*   batch= (const int*)d_in[2];
  const float* W1   = (const float*)d_in[3];
  const float* as1  = (const float*)d_in[4];
  const float* ad1  = (const float*)d_in[5];
  const float* b1   = (const float*)d_in[6];
  const float* W2   = (const float*)d_in[7];
  const float* as2  = (const float*)d_in[8];
  const float* ad2  = (const float*)d_in[9];
  const float* b2   = (const float*)d_in[10];
  const float* W3   = (const float*)d_in[11];
  const float* as3  = (const float*)d_in[12];
  const float* ad3  = (const float*)d_in[13];
  const float* b3   = (const float*)d_in[14];
  const float* fcw  = (const float*)d_in[15];
  const float* fcb  = (const float*)d_in[16];
  float* out = (float*)d_out;

  const int N = in_sizes[0] / 128;
  const int E = in_sizes[1] / 2;
  const int G = out_size;
  const int NB = (N + 255) >> 8;

  char* p = (char*)d_ws;
  auto alloc = [&](size_t bytes) -> void* {
    void* r = (void*)p;
    p += (bytes + 255) & ~(size_t)255;
    return r;
  };
  ushort* bufH   = (ushort*)alloc((size_t)N*128*sizeof(ushort));  // GEMM out (bf16)
  ushort* aggB   = (ushort*)alloc((size_t)N*128*sizeof(ushort));  // agg out L1/L2 (bf16)
  ushort* bufH3  = (ushort*)alloc((size_t)N*32*sizeof(ushort));   // GEMM3 out (bf16)
  float*  asrcA  = (float*)alloc((size_t)N*4*sizeof(float));
  float*  adstA  = (float*)alloc((size_t)N*4*sizeof(float));
  float*  asrcB  = (float*)alloc((size_t)N*4*sizeof(float));
  float*  adstB  = (float*)alloc((size_t)N*4*sizeof(float));
  int*    offsets= (int*)alloc((size_t)(N+1)*sizeof(int));
  int*    csr    = (int*)alloc((size_t)E*sizeof(int));
  uint*   tmp    = (uint*)alloc((size_t)E*sizeof(uint));
  int*    zeroR  = (int*)alloc(1024*sizeof(int));   // bCount[512] + gcursor[512]
  int*    bCount = zeroR;
  int*    gcursor= zeroR + 512;
  int*    gstart = (int*)alloc((size_t)(G+1)*sizeof(int));
  float*  pool   = (float*)alloc((size_t)G*16*sizeof(float));
  ushort* Wf1    = (ushort*)alloc(9*4*64*8*sizeof(ushort));
  ushort* Wf2    = (ushort*)alloc(9*4*64*8*sizeof(ushort));
  ushort* Wf3    = (ushort*)alloc(3*4*64*8*sizeof(ushort));

  hipMemsetAsync(zeroR, 0, 1024*sizeof(int), stream);

  const int NBb = (N + 255)/256;
  const int NH  = (E + 2047)/2048;
  // prep: wrep(21) + pool-zero(1) + bounds(NBb) + hist(NH) in one dispatch
  k_prep<<<22 + NBb + NH, 256, 0, stream>>>(W1, as1, ad1, Wf1, W2, as2, ad2, Wf2,
                                            W3, as3, ad3, Wf3, ei, E, bCount,
                                            batch, N, G, gstart, pool, NBb);
  k_scatA<<<(E+CHUNK-1)/CHUNK, 256, 0, stream>>>(ei, E, NB, bCount, gcursor, tmp);
  k_csr<<<NB, 256, 0, stream>>>(tmp, bCount, N, NB, offsets, csr);

  const int GB = (((N + 15)/16) + 3)/4;   // one 16-row chunk per wave
  const int NWB = (N + 3)/4;      // agg128: 4 nodes/block (1 per wave)
  const int NWB32 = (N + 15)/16;  // agg32pool: 16 nodes/block (4 per wave)
  // layer 1
  k_mgemm<8, true , 4><<<GB, 256, 0, stream>>>(x, Wf1, bufH, asrcA, adstA, N);
  k_agg128f<true><<<NWB, 256, 0, stream>>>(bufH, asrcA, adstA, offsets, csr, b1, aggB, N);
  // layer 2
  k_mgemm<8, false, 4><<<GB, 256, 0, stream>>>(aggB, Wf2, bufH, asrcB, adstB, N);
  k_agg128f<true><<<NWB, 256, 0, stream>>>(bufH, asrcB, adstB, offsets, csr, b2, aggB, N);
  // layer 3
  k_mgemm<2, false, 1><<<GB, 256, 0, stream>>>(aggB, Wf3, bufH3, asrcA, adstA, N);
  // layer-3 agg + readout dot + pool, then tiny finisher dispatch
  k_agg32pool<<<NWB32, 256, 0, stream>>>(bufH3, asrcA, adstA, offsets, csr,
                                         b3, fcw, batch, pool, N);
  k_poolfin<<<(G+255)/256, 256, 0, stream>>>(pool, gstart, fcb, out, G);
}